// Round 9
// baseline (744.178 us; speedup 1.0000x reference)
//
#include <hip/hip_runtime.h>
#include <hip/hip_bf16.h>

#define N_NODES 50000
#define T_SEQ 24
#define D_IN 16
#define H_DIM 64
#define SD 9
#define E_EDGES 1600000
#define NUM_GRAPHS 500

typedef _Float16 half8 __attribute__((ext_vector_type(8)));
typedef _Float16 half4 __attribute__((ext_vector_type(4)));
typedef float floatx4 __attribute__((ext_vector_type(4)));

__device__ __forceinline__ float fsig(float x) { return 1.0f / (1.0f + __expf(-x)); }
__device__ __forceinline__ float ftanh(float x) { return 1.0f - 2.0f / (1.0f + __expf(2.0f * x)); }

// ---------------------------------------------------------------------------
// MFMA LSTM v7: BARRIER-FREE, 1 wave per block, 16 nodes per wave.
// Swapped operands: G^T[256,16] = W_all[256,80] x [h;x;1][80,16] so D's col =
// node and the whole recurrence is wave-private. W_all as 48 A-frags in VGPRs
// (192 regs, loaded once). Bias folded into MFMA via k=16 const-1 slot of the
// x K-tile. h kept in a 2KB wave-private LDS buffer (XOR-swizzled, ~2-way
// conflicts = free); NO __syncthreads in the entire t-loop.
// ---------------------------------------------------------------------------
__global__ __launch_bounds__(64) void lstm_mfma(
    const float* __restrict__ x,
    const float* __restrict__ W_ih, const float* __restrict__ W_hh,
    const float* __restrict__ b_ih, const float* __restrict__ b_hh,
    float* __restrict__ hout)
{
    __shared__ _Float16 hbuf[1024];     // [node][unit] f16, swizzled, wave-private
    char* hB = (char*)hbuf;

    const int l  = threadIdx.x;
    const int nl = l & 15;              // node within tile (D/B col)
    const int g  = l >> 4;              // k-group
    const int node = blockIdx.x * 16 + nl;   // 3125*16 = 50000 exactly

    // ---- W_all A-fragments, loaded once: aw[class][rtl][q] ----
    // A row = 64*class + 16*rtl + nl ; k(within MFMA) = 8*g + e
    // q0: h[0:32), q1: h[32:64), q2: x[0:16) at g<2, bias at g==2,e==0, else 0
    half8 aw[4][4][3];
#pragma unroll
    for (int c = 0; c < 4; c++) {
#pragma unroll
        for (int rtl = 0; rtl < 4; rtl++) {
            const int row = 64 * c + 16 * rtl + nl;
#pragma unroll
            for (int q = 0; q < 2; q++) {
                const float* p = W_hh + row * 64 + q * 32 + 8 * g;
                half8 f;
#pragma unroll
                for (int e = 0; e < 8; e++) f[e] = (_Float16)p[e];
                aw[c][rtl][q] = f;
            }
            half8 f = {(_Float16)0, (_Float16)0, (_Float16)0, (_Float16)0,
                       (_Float16)0, (_Float16)0, (_Float16)0, (_Float16)0};
            if (g < 2) {
                const float* p = W_ih + row * 16 + 8 * g;
#pragma unroll
                for (int e = 0; e < 8; e++) f[e] = (_Float16)p[e];
            } else if (g == 2) {
                f[0] = (_Float16)(b_ih[row] + b_hh[row]);
            }
            aw[c][rtl][2] = f;
        }
    }

    // ---- swizzled LDS byte offsets (elem = nl*64 + u, byte ^= (nl&7)<<4) ----
    const int swz = (nl & 7) << 4;
    int wb[4];                           // write: u0 = 16*rtl + 4*g (8B half4)
#pragma unroll
    for (int rtl = 0; rtl < 4; rtl++) wb[rtl] = (nl * 128 + 32 * rtl + 8 * g) ^ swz;
    int rb[2];                           // read: u0 = 32*q + 8*g (16B half8)
#pragma unroll
    for (int q = 0; q < 2; q++) rb[q] = (nl * 128 + 64 * q + 16 * g) ^ swz;

    // zero h (64 lanes x 32B = 2048B), wave-private so lgkmcnt ordering suffices
    {
        floatx4 z = {0.0f, 0.0f, 0.0f, 0.0f};
        *reinterpret_cast<floatx4*>(hB + l * 32) = z;
        *reinterpret_cast<floatx4*>(hB + l * 32 + 16) = z;
    }

    // ---- x stream (g<2 real halves; g>=2 load dup of g&1, ignored) ----
    const float* xp = x + (size_t)node * 384 + 8 * (g & 1);
    float4 xc0 = *reinterpret_cast<const float4*>(xp);
    float4 xc1 = *reinterpret_cast<const float4*>(xp + 4);

    float c_reg[4][4];
#pragma unroll
    for (int rtl = 0; rtl < 4; rtl++)
#pragma unroll
        for (int j = 0; j < 4; j++) c_reg[rtl][j] = 0.0f;

#pragma unroll 1
    for (int t = 0; t < T_SEQ; t++) {
        // build B q2 fragment: x | 1-slot | zeros
        half8 bx = {(_Float16)0, (_Float16)0, (_Float16)0, (_Float16)0,
                    (_Float16)0, (_Float16)0, (_Float16)0, (_Float16)0};
        if (g < 2) {
            bx[0] = (_Float16)xc0.x; bx[1] = (_Float16)xc0.y;
            bx[2] = (_Float16)xc0.z; bx[3] = (_Float16)xc0.w;
            bx[4] = (_Float16)xc1.x; bx[5] = (_Float16)xc1.y;
            bx[6] = (_Float16)xc1.z; bx[7] = (_Float16)xc1.w;
        } else if (g == 2) {
            bx[0] = (_Float16)1.0f;   // bias slot (k=16): B=1, A=bias
        }
        // prefetch next step's x
        if (t < T_SEQ - 1) {
            xc0 = *reinterpret_cast<const float4*>(xp + (t + 1) * 16);
            xc1 = *reinterpret_cast<const float4*>(xp + (t + 1) * 16 + 4);
        }
        // h B-fragments from private LDS
        const half8 bh0 = *reinterpret_cast<const half8*>(hB + rb[0]);
        const half8 bh1 = *reinterpret_cast<const half8*>(hB + rb[1]);

#pragma unroll
        for (int rtl = 0; rtl < 4; rtl++) {
            floatx4 ai = {0.0f, 0.0f, 0.0f, 0.0f};
            floatx4 af = {0.0f, 0.0f, 0.0f, 0.0f};
            floatx4 ag = {0.0f, 0.0f, 0.0f, 0.0f};
            floatx4 ao = {0.0f, 0.0f, 0.0f, 0.0f};
            ai = __builtin_amdgcn_mfma_f32_16x16x32_f16(aw[0][rtl][0], bh0, ai, 0, 0, 0);
            af = __builtin_amdgcn_mfma_f32_16x16x32_f16(aw[1][rtl][0], bh0, af, 0, 0, 0);
            ag = __builtin_amdgcn_mfma_f32_16x16x32_f16(aw[2][rtl][0], bh0, ag, 0, 0, 0);
            ao = __builtin_amdgcn_mfma_f32_16x16x32_f16(aw[3][rtl][0], bh0, ao, 0, 0, 0);
            ai = __builtin_amdgcn_mfma_f32_16x16x32_f16(aw[0][rtl][1], bh1, ai, 0, 0, 0);
            af = __builtin_amdgcn_mfma_f32_16x16x32_f16(aw[1][rtl][1], bh1, af, 0, 0, 0);
            ag = __builtin_amdgcn_mfma_f32_16x16x32_f16(aw[2][rtl][1], bh1, ag, 0, 0, 0);
            ao = __builtin_amdgcn_mfma_f32_16x16x32_f16(aw[3][rtl][1], bh1, ao, 0, 0, 0);
            ai = __builtin_amdgcn_mfma_f32_16x16x32_f16(aw[0][rtl][2], bx, ai, 0, 0, 0);
            af = __builtin_amdgcn_mfma_f32_16x16x32_f16(aw[1][rtl][2], bx, af, 0, 0, 0);
            ag = __builtin_amdgcn_mfma_f32_16x16x32_f16(aw[2][rtl][2], bx, ag, 0, 0, 0);
            ao = __builtin_amdgcn_mfma_f32_16x16x32_f16(aw[3][rtl][2], bx, ao, 0, 0, 0);

            // epilogue: unit u = 16*rtl + 4*g + j, node nl
            float hv0, hv1, hv2, hv3;
#pragma unroll
            for (int j = 0; j < 4; j++) {
                const float ig = fsig(ai[j]);
                const float fg = fsig(af[j]);
                const float gg = ftanh(ag[j]);
                const float og = fsig(ao[j]);
                const float cv = fg * c_reg[rtl][j] + ig * gg;
                c_reg[rtl][j] = cv;
                const float hv = og * ftanh(cv);
                if (j == 0) hv0 = hv; else if (j == 1) hv1 = hv;
                else if (j == 2) hv2 = hv; else hv3 = hv;
            }
            half4 hh = {(_Float16)hv0, (_Float16)hv1, (_Float16)hv2, (_Float16)hv3};
            *reinterpret_cast<half4*>(hB + wb[rtl]) = hh;
            if (t == T_SEQ - 1) {
                float4 o4 = {hv0, hv1, hv2, hv3};
                *reinterpret_cast<float4*>(&hout[(size_t)node * 64 + 16 * rtl + 4 * g]) = o4;
            }
        }
    }
}

// ---------------------------------------------------------------------------
// CSR build: histogram -> scan -> fill
// ---------------------------------------------------------------------------
__global__ void count_deg(const int* __restrict__ ei, int* __restrict__ cnt) {
    int e = blockIdx.x * 256 + threadIdx.x;
    if (e < E_EDGES) {
        int c = ei[E_EDGES + e];
        if ((unsigned)c < N_NODES) atomicAdd(&cnt[c], 1);
    }
}

__global__ void make_dis(const int* __restrict__ cnt, float* __restrict__ dis) {
    int i = blockIdx.x * 256 + threadIdx.x;
    if (i < N_NODES) dis[i] = rsqrtf((float)(cnt[i] + 1));  // +1 self-loop
}

__global__ __launch_bounds__(1024) void scan_csr(const int* __restrict__ cnt,
                                                 int* __restrict__ ptr,
                                                 int* __restrict__ cursor)
{
    __shared__ int wsum[16];
    __shared__ int carry_s;
    const int tid = threadIdx.x;
    const int lane = tid & 63;
    const int wv = tid >> 6;
    if (tid == 0) carry_s = 0;
    __syncthreads();
    for (int base = 0; base < N_NODES; base += 1024) {
        const int i = base + tid;
        const int orig = (i < N_NODES) ? cnt[i] : 0;
        int v = orig;
#pragma unroll
        for (int d = 1; d < 64; d <<= 1) {
            int nb = __shfl_up(v, d, 64);
            if (lane >= d) v += nb;
        }
        if (lane == 63) wsum[wv] = v;
        __syncthreads();
        if (wv == 0) {
            int s = (lane < 16) ? wsum[lane] : 0;
#pragma unroll
            for (int d = 1; d < 16; d <<= 1) {
                int nb = __shfl_up(s, d, 64);
                if (lane >= d) s += nb;
            }
            if (lane < 16) wsum[lane] = s;
        }
        __syncthreads();
        const int waveoff = (wv > 0) ? wsum[wv - 1] : 0;
        const int excl = carry_s + waveoff + v - orig;
        if (i < N_NODES) { ptr[i] = excl; cursor[i] = excl; }
        __syncthreads();
        if (tid == 1023) carry_s += wsum[15];
        __syncthreads();
    }
    if (tid == 0) ptr[N_NODES] = carry_s;
}

__global__ void fill_csr(const int* __restrict__ ei, int* __restrict__ cursor,
                         int* __restrict__ csr)
{
    int e = blockIdx.x * 256 + threadIdx.x;
    if (e < E_EDGES) {
        int r = ei[e];
        int c = ei[E_EDGES + e];
        if ((unsigned)r < N_NODES && (unsigned)c < N_NODES) {
            int slot = atomicAdd(&cursor[c], 1);
            csr[slot] = r;
        }
    }
}

// ---------------------------------------------------------------------------
// Weight pre-combination: Wc = Wg1 @ W1  [64 x 73], bc = Wg1 @ l1_b  [64]
// ---------------------------------------------------------------------------
__global__ void combine_w(const float* __restrict__ g1W, const float* __restrict__ l1W,
                          const float* __restrict__ l1b,
                          float* __restrict__ Wc, float* __restrict__ bc)
{
    int idx = blockIdx.x * 256 + threadIdx.x;
    int o = idx / 74, j = idx - o * 74;
    if (o >= 64) return;
    float acc = 0.0f;
    if (j < 73) {
#pragma unroll 8
        for (int k = 0; k < 64; k++) acc += g1W[o * 64 + k] * l1W[k * 73 + j];
        Wc[o * 73 + j] = acc;
    } else {
#pragma unroll 8
        for (int k = 0; k < 64; k++) acc += g1W[o * 64 + k] * l1b[k];
        bc[o] = acc;
    }
}

// ---------------------------------------------------------------------------
// xform1: m[n][o] = dis[n] * (sum_j Wc[o][j]*[h;sdi][n][j] + bc[o])
// ---------------------------------------------------------------------------
__global__ __launch_bounds__(256) void xform1(
    const float* __restrict__ h, const float* __restrict__ sdi,
    const float* __restrict__ Wc, const float* __restrict__ bc,
    const float* __restrict__ dis, float* __restrict__ m)
{
    __shared__ float wlds[64 * 73];
    __shared__ float blds[64];
    __shared__ float row[4][80];
    for (int i = threadIdx.x; i < 64 * 73; i += 256) wlds[i] = Wc[i];
    if (threadIdx.x < 64) blds[threadIdx.x] = bc[threadIdx.x];
    __syncthreads();
    const int wv = threadIdx.x >> 6, o = threadIdx.x & 63;
    for (int n = blockIdx.x * 4 + wv; n < N_NODES; n += gridDim.x * 4) {
        row[wv][o] = h[(size_t)n * 64 + o];
        if (o < SD) row[wv][64 + o] = sdi[(size_t)n * SD + o];
        __builtin_amdgcn_wave_barrier();
        float acc = blds[o];
#pragma unroll 8
        for (int j = 0; j < 73; j++) acc += wlds[o * 73 + j] * row[wv][j];
        __builtin_amdgcn_wave_barrier();
        m[(size_t)n * 64 + o] = acc * dis[n];
    }
}

// ---------------------------------------------------------------------------
// fused gather + GCN1 finalize + GCN2 transform (z1 never materialized):
// z1_f = relu(dis*(gather_f + self_f) + b1_f);  s2 = dis * sum_f z1_f*W2_f
// ---------------------------------------------------------------------------
__global__ __launch_bounds__(256) void gatherfin1s2(
    const int* __restrict__ ptr, const int* __restrict__ csr,
    const float* __restrict__ m, const float* __restrict__ dis,
    const float* __restrict__ b1, const float* __restrict__ W2,
    float* __restrict__ s2)
{
    const int wid = (blockIdx.x * 256 + threadIdx.x) >> 6;
    const int f = threadIdx.x & 63;
    if (wid >= N_NODES) return;
    const int b = ptr[wid];
    const int e = ptr[wid + 1];
    float a0 = 0.0f, a1 = 0.0f, a2 = 0.0f, a3 = 0.0f;
    int i = b;
    for (; i + 4 <= e; i += 4) {
        const int s0 = csr[i], s1 = csr[i + 1], sc2 = csr[i + 2], s3 = csr[i + 3];
        a0 += m[(size_t)s0 * 64 + f];
        a1 += m[(size_t)s1 * 64 + f];
        a2 += m[(size_t)sc2 * 64 + f];
        a3 += m[(size_t)s3 * 64 + f];
    }
    for (; i < e; i++) a0 += m[(size_t)csr[i] * 64 + f];
    const float self = m[(size_t)wid * 64 + f];
    const float dn = dis[wid];
    const float v = dn * (((a0 + a1) + (a2 + a3)) + self) + b1[f];
    const float z1 = v > 0.0f ? v : 0.0f;
    // wave dot with W2
    float p = z1 * W2[f];
#pragma unroll
    for (int off = 32; off >= 1; off >>= 1) p += __shfl_xor(p, off, 64);
    if (f == 0) s2[wid] = dn * p;
}

__global__ void gather2fin(const int* __restrict__ ptr, const int* __restrict__ csr,
                           const float* __restrict__ s2, const float* __restrict__ dis,
                           const float* __restrict__ b2, const int* __restrict__ batch,
                           float* __restrict__ gsum, float* __restrict__ gcnt)
{
    int n = blockIdx.x * 256 + threadIdx.x;
    if (n >= N_NODES) return;
    const int b = ptr[n];
    const int e = ptr[n + 1];
    float a0 = 0.0f, a1 = 0.0f, a2 = 0.0f, a3 = 0.0f;
    int i = b;
    for (; i + 4 <= e; i += 4) {
        a0 += s2[csr[i]];
        a1 += s2[csr[i + 1]];
        a2 += s2[csr[i + 2]];
        a3 += s2[csr[i + 3]];
    }
    for (; i < e; i++) a0 += s2[csr[i]];
    const float z2 = dis[n] * (((a0 + a1) + (a2 + a3)) + s2[n]) + b2[0];
    const int g = batch[n];
    if ((unsigned)g < NUM_GRAPHS) {
        atomicAdd(&gsum[g], z2);
        atomicAdd(&gcnt[g], 1.0f);
    }
}

__global__ void pooldiv(const float* __restrict__ gsum, const float* __restrict__ gcnt,
                        float* __restrict__ out)
{
    int g = blockIdx.x * 256 + threadIdx.x;
    if (g < NUM_GRAPHS) out[g] = gsum[g] / fmaxf(gcnt[g], 1.0f);
}

// ---------------------------------------------------------------------------
extern "C" void kernel_launch(void* const* d_in, const int* in_sizes, int n_in,
                              void* d_out, int out_size, void* d_ws, size_t ws_size,
                              hipStream_t stream)
{
    const float* x     = (const float*)d_in[0];
    const float* sdi   = (const float*)d_in[1];
    const int*   ei    = (const int*)d_in[2];
    const int*   batch = (const int*)d_in[3];
    const float* W_ih  = (const float*)d_in[4];
    const float* W_hh  = (const float*)d_in[5];
    const float* b_ih  = (const float*)d_in[6];
    const float* b_hh  = (const float*)d_in[7];
    const float* l1_W  = (const float*)d_in[8];
    const float* l1_b  = (const float*)d_in[9];
    const float* g1_W  = (const float*)d_in[10];
    const float* g1_b  = (const float*)d_in[11];
    const float* g2_W  = (const float*)d_in[12];
    const float* g2_b  = (const float*)d_in[13];
    float* out = (float*)d_out;

    // workspace layout
    float* ws   = (float*)d_ws;
    float* A    = ws;                 // lstm h
    float* C    = ws + 6400000;       // m
    float* dis  = ws + 9600000;
    float* s2   = dis + 50000;
    float* gsum = s2 + 50000;
    float* gcnt = gsum + 500;
    int* cnt    = (int*)(gcnt + 500);
    int* ptr    = cnt + 50000;        // 50001 entries
    int* cursor = ptr + 50001;
    int* csr    = cursor + 50000;     // 1.6M entries
    float* Wc   = (float*)(csr + E_EDGES);
    float* bc   = Wc + 64 * 73;

    const int nodeBlocks = (N_NODES + 255) / 256;
    const int featBlocks = (N_NODES * 64 + 255) / 256;   // 12500
    const int edgeBlocks = (E_EDGES + 255) / 256;

    // 1. LSTM -> A   (16 nodes per 1-wave block, barrier-free)
    lstm_mfma<<<N_NODES / 16, 64, 0, stream>>>(x, W_ih, W_hh, b_ih, b_hh, A);

    // 2. CSR build + normalization + combined weights
    hipMemsetAsync(cnt, 0, 50000 * sizeof(int), stream);
    hipMemsetAsync(gsum, 0, 1000 * sizeof(float), stream);
    count_deg<<<edgeBlocks, 256, 0, stream>>>(ei, cnt);
    make_dis<<<nodeBlocks, 256, 0, stream>>>(cnt, dis);
    scan_csr<<<1, 1024, 0, stream>>>(cnt, ptr, cursor);
    fill_csr<<<edgeBlocks, 256, 0, stream>>>(ei, cursor, csr);
    combine_w<<<(64 * 74 + 255) / 256, 256, 0, stream>>>(g1_W, l1_W, l1_b, Wc, bc);

    // 3. fused l1 + gcn1-transform: m -> C
    xform1<<<1024, 256, 0, stream>>>(A, sdi, Wc, bc, dis, C);

    // 4. fused gather + finalize + gcn2 transform: s2 (z1 never materialized)
    gatherfin1s2<<<featBlocks, 256, 0, stream>>>(ptr, csr, C, dis, g1_b, g2_W, s2);

    // 5. gather2 + pool
    gather2fin<<<nodeBlocks, 256, 0, stream>>>(ptr, csr, s2, dis, g2_b, batch, gsum, gcnt);
    pooldiv<<<2, 256, 0, stream>>>(gsum, gcnt, out);
}

// Round 10
// 610.369 us; speedup vs baseline: 1.2192x; 1.2192x over previous
//
#include <hip/hip_runtime.h>
#include <hip/hip_bf16.h>

#define N_NODES 50000
#define T_SEQ 24
#define D_IN 16
#define H_DIM 64
#define SD 9
#define E_EDGES 1600000
#define NUM_GRAPHS 500

typedef _Float16 half8 __attribute__((ext_vector_type(8)));
typedef _Float16 half4 __attribute__((ext_vector_type(4)));
typedef float floatx4 __attribute__((ext_vector_type(4)));

// Fast activations: __fdividef -> v_rcp + mul (plain f32 '/' emits the
// ~10-op div_scale/div_fmas/div_fixup sequence -- was the bulk of VALUBusy).
__device__ __forceinline__ float fsig(float x) {
    return __fdividef(1.0f, 1.0f + __expf(-x));
}
__device__ __forceinline__ float ftanh(float x) {
    return 1.0f - __fdividef(2.0f, 1.0f + __expf(2.0f * x));
}

// ---------------------------------------------------------------------------
// MFMA LSTM v6 (round-8 verified structure): 16 nodes/block, 4 waves,
// grid = 3125. LDS 16KB: h dbuf 2x2KB + x (24 steps, f16) 12KB. VGPR ~60.
// One barrier per timestep. Do NOT force min-waves in launch_bounds (r5/r6:
// forced occupancy -> 0.5-1.3GB scratch spill).
// ---------------------------------------------------------------------------
__global__ __launch_bounds__(256, 2) void lstm_mfma(
    const float* __restrict__ x,
    const float* __restrict__ W_ih, const float* __restrict__ W_hh,
    const float* __restrict__ b_ih, const float* __restrict__ b_hh,
    float* __restrict__ hout)
{
    __shared__ _Float16 smem[2048 + 24 * 16 * 16];
    _Float16* hb0 = smem;
    _Float16* hb1 = smem + 1024;
    _Float16* xbuf = smem + 2048;   // [t][n][d] f16, all 24 steps

    const int tid  = threadIdx.x;
    const int lane = tid & 63;
    const int w    = tid >> 6;      // wave id: unit quarter
    const int lr   = lane & 15;
    const int lg   = lane >> 4;
    const int nbase = blockIdx.x * 16;   // 3125 * 16 = 50000 exactly

    // ---- B fragments (weights), loaded once ----
    half8 bw[4][3];
    float bias[4];
#pragma unroll
    for (int ct = 0; ct < 4; ct++) {
        const int r = ct * 64 + w * 16 + lr;
        bias[ct] = b_ih[r] + b_hh[r];
#pragma unroll
        for (int kt = 0; kt < 2; kt++) {
            const float* p = W_hh + r * 64 + kt * 32 + 8 * lg;
            half8 f;
#pragma unroll
            for (int e = 0; e < 8; e++) f[e] = (_Float16)p[e];
            bw[ct][kt] = f;
        }
        half8 f = {(_Float16)0, (_Float16)0, (_Float16)0, (_Float16)0,
                   (_Float16)0, (_Float16)0, (_Float16)0, (_Float16)0};
        if (lg < 2) {
            const float* p = W_ih + r * 16 + 8 * lg;
#pragma unroll
            for (int e = 0; e < 8; e++) f[e] = (_Float16)p[e];
        }
        bw[ct][2] = f;
    }

    // ---- stage x: 16 nodes * 384 floats = 1536 float4, coalesced ----
#pragma unroll
    for (int it = 0; it < 6; it++) {
        const int f4 = tid + it * 256;        // 0..1535
        const int fi = f4 * 4;
        const int n  = fi / 384;
        const int rem = fi - n * 384;
        const int t  = rem >> 4;
        const int d  = rem & 15;
        const float4 v = *reinterpret_cast<const float4*>(
            x + (size_t)(nbase + n) * 384 + rem);
        half4 hv = {(_Float16)v.x, (_Float16)v.y, (_Float16)v.z, (_Float16)v.w};
        *reinterpret_cast<half4*>(&xbuf[t * 256 + n * 16 + d]) = hv;
    }
    // zero h buffer 0 (1024 f16 = 512 ints)
    if (tid < 128) { ((int*)hb0)[tid] = 0; ((int*)hb0)[tid + 128] = 0; ((int*)hb0)[tid + 256] = 0; ((int*)hb0)[tid + 384] = 0; }

    // ---- precomputed swizzled LDS offsets (node=lr; u = w*16+lr) ----
    const int u = w * 16 + lr;
    int ra[2];       // h-read A-frag
#pragma unroll
    for (int kt = 0; kt < 2; kt++)
        ra[kt] = lr * 64 + 8 * ((4 * kt + lg) ^ (lr & 7));
    int woff[4];     // h-write
#pragma unroll
    for (int j = 0; j < 4; j++) {
        const int nj = 4 * lg + j;
        woff[j] = nj * 64 + (u & 7) + 8 * ((u >> 3) ^ (nj & 7));
    }
    const int xro = lr * 16 + 8 * (lg & 1);   // x-read: addr = tl*256 + xro

    float c_reg[4];
#pragma unroll
    for (int j = 0; j < 4; j++) c_reg[j] = 0.0f;

    __syncthreads();

    auto step = [&](int tl, bool last, _Float16* hR, _Float16* hW) {
        floatx4 acc[4];
#pragma unroll
        for (int ct = 0; ct < 4; ct++) {
            floatx4 a = {bias[ct], bias[ct], bias[ct], bias[ct]};
            acc[ct] = a;
        }
        const half8 ax = *reinterpret_cast<const half8*>(&xbuf[tl * 256 + xro]);
        const half8 ah0 = *reinterpret_cast<const half8*>(&hR[ra[0]]);
        const half8 ah1 = *reinterpret_cast<const half8*>(&hR[ra[1]]);
#pragma unroll
        for (int ct = 0; ct < 4; ct++)
            acc[ct] = __builtin_amdgcn_mfma_f32_16x16x32_f16(ah0, bw[ct][0], acc[ct], 0, 0, 0);
#pragma unroll
        for (int ct = 0; ct < 4; ct++)
            acc[ct] = __builtin_amdgcn_mfma_f32_16x16x32_f16(ah1, bw[ct][1], acc[ct], 0, 0, 0);
#pragma unroll
        for (int ct = 0; ct < 4; ct++)
            acc[ct] = __builtin_amdgcn_mfma_f32_16x16x32_f16(ax, bw[ct][2], acc[ct], 0, 0, 0);

#pragma unroll
        for (int j = 0; j < 4; j++) {
            const float ig = fsig(acc[0][j]);
            const float fg = fsig(acc[1][j]);
            const float gg = ftanh(acc[2][j]);
            const float og = fsig(acc[3][j]);
            const float cv = fg * c_reg[j] + ig * gg;
            c_reg[j] = cv;
            const float hv = og * ftanh(cv);
            hW[woff[j]] = (_Float16)hv;
            if (last) {
                const int gn = nbase + 4 * lg + j;
                hout[(size_t)gn * H_DIM + u] = hv;
            }
        }
        __syncthreads();
    };

    for (int tb = 0; tb < 6; tb++) {
        const int t0 = tb * 4;
        step(t0 + 0, false, hb0, hb1);
        step(t0 + 1, false, hb1, hb0);
        step(t0 + 2, false, hb0, hb1);
        step(t0 + 3, tb == 5, hb1, hb0);
    }
}

// ---------------------------------------------------------------------------
// CSR build: histogram -> scan -> fill
// ---------------------------------------------------------------------------
__global__ void count_deg(const int* __restrict__ ei, int* __restrict__ cnt) {
    int e = blockIdx.x * 256 + threadIdx.x;
    if (e < E_EDGES) {
        int c = ei[E_EDGES + e];
        if ((unsigned)c < N_NODES) atomicAdd(&cnt[c], 1);
    }
}

__global__ void make_dis(const int* __restrict__ cnt, float* __restrict__ dis) {
    int i = blockIdx.x * 256 + threadIdx.x;
    if (i < N_NODES) dis[i] = rsqrtf((float)(cnt[i] + 1));  // +1 self-loop
}

__global__ __launch_bounds__(1024) void scan_csr(const int* __restrict__ cnt,
                                                 int* __restrict__ ptr,
                                                 int* __restrict__ cursor)
{
    __shared__ int wsum[16];
    __shared__ int carry_s;
    const int tid = threadIdx.x;
    const int lane = tid & 63;
    const int wv = tid >> 6;
    if (tid == 0) carry_s = 0;
    __syncthreads();
    for (int base = 0; base < N_NODES; base += 1024) {
        const int i = base + tid;
        const int orig = (i < N_NODES) ? cnt[i] : 0;
        int v = orig;
#pragma unroll
        for (int d = 1; d < 64; d <<= 1) {
            int nb = __shfl_up(v, d, 64);
            if (lane >= d) v += nb;
        }
        if (lane == 63) wsum[wv] = v;
        __syncthreads();
        if (wv == 0) {
            int s = (lane < 16) ? wsum[lane] : 0;
#pragma unroll
            for (int d = 1; d < 16; d <<= 1) {
                int nb = __shfl_up(s, d, 64);
                if (lane >= d) s += nb;
            }
            if (lane < 16) wsum[lane] = s;
        }
        __syncthreads();
        const int waveoff = (wv > 0) ? wsum[wv - 1] : 0;
        const int excl = carry_s + waveoff + v - orig;
        if (i < N_NODES) { ptr[i] = excl; cursor[i] = excl; }
        __syncthreads();
        if (tid == 1023) carry_s += wsum[15];
        __syncthreads();
    }
    if (tid == 0) ptr[N_NODES] = carry_s;
}

__global__ void fill_csr(const int* __restrict__ ei, int* __restrict__ cursor,
                         int* __restrict__ csr)
{
    int e = blockIdx.x * 256 + threadIdx.x;
    if (e < E_EDGES) {
        int r = ei[e];
        int c = ei[E_EDGES + e];
        if ((unsigned)r < N_NODES && (unsigned)c < N_NODES) {
            int slot = atomicAdd(&cursor[c], 1);
            csr[slot] = r;
        }
    }
}

// ---------------------------------------------------------------------------
// Weight pre-combination: Wc = Wg1 @ W1  [64 x 73], bc = Wg1 @ l1_b  [64]
// ---------------------------------------------------------------------------
__global__ void combine_w(const float* __restrict__ g1W, const float* __restrict__ l1W,
                          const float* __restrict__ l1b,
                          float* __restrict__ Wc, float* __restrict__ bc)
{
    int idx = blockIdx.x * 256 + threadIdx.x;
    int o = idx / 74, j = idx - o * 74;
    if (o >= 64) return;
    float acc = 0.0f;
    if (j < 73) {
#pragma unroll 8
        for (int k = 0; k < 64; k++) acc += g1W[o * 64 + k] * l1W[k * 73 + j];
        Wc[o * 73 + j] = acc;
    } else {
#pragma unroll 8
        for (int k = 0; k < 64; k++) acc += g1W[o * 64 + k] * l1b[k];
        bc[o] = acc;
    }
}

// ---------------------------------------------------------------------------
// xform1: m[n][o] = dis[n] * (sum_j Wc[o][j]*[h;sdi][n][j] + bc[o])
// ---------------------------------------------------------------------------
__global__ __launch_bounds__(256) void xform1(
    const float* __restrict__ h, const float* __restrict__ sdi,
    const float* __restrict__ Wc, const float* __restrict__ bc,
    const float* __restrict__ dis, float* __restrict__ m)
{
    __shared__ float wlds[64 * 73];
    __shared__ float blds[64];
    __shared__ float row[4][80];
    for (int i = threadIdx.x; i < 64 * 73; i += 256) wlds[i] = Wc[i];
    if (threadIdx.x < 64) blds[threadIdx.x] = bc[threadIdx.x];
    __syncthreads();
    const int wv = threadIdx.x >> 6, o = threadIdx.x & 63;
    for (int n = blockIdx.x * 4 + wv; n < N_NODES; n += gridDim.x * 4) {
        row[wv][o] = h[(size_t)n * 64 + o];
        if (o < SD) row[wv][64 + o] = sdi[(size_t)n * SD + o];
        __builtin_amdgcn_wave_barrier();
        float acc = blds[o];
#pragma unroll 8
        for (int j = 0; j < 73; j++) acc += wlds[o * 73 + j] * row[wv][j];
        __builtin_amdgcn_wave_barrier();
        m[(size_t)n * 64 + o] = acc * dis[n];
    }
}

// ---------------------------------------------------------------------------
// fused gather + GCN1 finalize + GCN2 transform (z1 never materialized)
// ---------------------------------------------------------------------------
__global__ __launch_bounds__(256) void gatherfin1s2(
    const int* __restrict__ ptr, const int* __restrict__ csr,
    const float* __restrict__ m, const float* __restrict__ dis,
    const float* __restrict__ b1, const float* __restrict__ W2,
    float* __restrict__ s2)
{
    const int wid = (blockIdx.x * 256 + threadIdx.x) >> 6;
    const int f = threadIdx.x & 63;
    if (wid >= N_NODES) return;
    const int b = ptr[wid];
    const int e = ptr[wid + 1];
    float a0 = 0.0f, a1 = 0.0f, a2 = 0.0f, a3 = 0.0f;
    int i = b;
    for (; i + 4 <= e; i += 4) {
        const int s0 = csr[i], s1 = csr[i + 1], sc2 = csr[i + 2], s3 = csr[i + 3];
        a0 += m[(size_t)s0 * 64 + f];
        a1 += m[(size_t)s1 * 64 + f];
        a2 += m[(size_t)sc2 * 64 + f];
        a3 += m[(size_t)s3 * 64 + f];
    }
    for (; i < e; i++) a0 += m[(size_t)csr[i] * 64 + f];
    const float self = m[(size_t)wid * 64 + f];
    const float dn = dis[wid];
    const float v = dn * (((a0 + a1) + (a2 + a3)) + self) + b1[f];
    const float z1 = v > 0.0f ? v : 0.0f;
    float p = z1 * W2[f];
#pragma unroll
    for (int off = 32; off >= 1; off >>= 1) p += __shfl_xor(p, off, 64);
    if (f == 0) s2[wid] = dn * p;
}

__global__ void gather2fin(const int* __restrict__ ptr, const int* __restrict__ csr,
                           const float* __restrict__ s2, const float* __restrict__ dis,
                           const float* __restrict__ b2, const int* __restrict__ batch,
                           float* __restrict__ gsum, float* __restrict__ gcnt)
{
    int n = blockIdx.x * 256 + threadIdx.x;
    if (n >= N_NODES) return;
    const int b = ptr[n];
    const int e = ptr[n + 1];
    float a0 = 0.0f, a1 = 0.0f, a2 = 0.0f, a3 = 0.0f;
    int i = b;
    for (; i + 4 <= e; i += 4) {
        a0 += s2[csr[i]];
        a1 += s2[csr[i + 1]];
        a2 += s2[csr[i + 2]];
        a3 += s2[csr[i + 3]];
    }
    for (; i < e; i++) a0 += s2[csr[i]];
    const float z2 = dis[n] * (((a0 + a1) + (a2 + a3)) + s2[n]) + b2[0];
    const int g = batch[n];
    if ((unsigned)g < NUM_GRAPHS) {
        atomicAdd(&gsum[g], z2);
        atomicAdd(&gcnt[g], 1.0f);
    }
}

__global__ void pooldiv(const float* __restrict__ gsum, const float* __restrict__ gcnt,
                        float* __restrict__ out)
{
    int g = blockIdx.x * 256 + threadIdx.x;
    if (g < NUM_GRAPHS) out[g] = gsum[g] / fmaxf(gcnt[g], 1.0f);
}

// ---------------------------------------------------------------------------
extern "C" void kernel_launch(void* const* d_in, const int* in_sizes, int n_in,
                              void* d_out, int out_size, void* d_ws, size_t ws_size,
                              hipStream_t stream)
{
    const float* x     = (const float*)d_in[0];
    const float* sdi   = (const float*)d_in[1];
    const int*   ei    = (const int*)d_in[2];
    const int*   batch = (const int*)d_in[3];
    const float* W_ih  = (const float*)d_in[4];
    const float* W_hh  = (const float*)d_in[5];
    const float* b_ih  = (const float*)d_in[6];
    const float* b_hh  = (const float*)d_in[7];
    const float* l1_W  = (const float*)d_in[8];
    const float* l1_b  = (const float*)d_in[9];
    const float* g1_W  = (const float*)d_in[10];
    const float* g1_b  = (const float*)d_in[11];
    const float* g2_W  = (const float*)d_in[12];
    const float* g2_b  = (const float*)d_in[13];
    float* out = (float*)d_out;

    // workspace layout
    float* ws   = (float*)d_ws;
    float* A    = ws;                 // lstm h
    float* C    = ws + 6400000;       // m
    float* dis  = ws + 9600000;
    float* s2   = dis + 50000;
    float* gsum = s2 + 50000;
    float* gcnt = gsum + 500;
    int* cnt    = (int*)(gcnt + 500);
    int* ptr    = cnt + 50000;        // 50001 entries
    int* cursor = ptr + 50001;
    int* csr    = cursor + 50000;     // 1.6M entries
    float* Wc   = (float*)(csr + E_EDGES);
    float* bc   = Wc + 64 * 73;

    const int nodeBlocks = (N_NODES + 255) / 256;
    const int featBlocks = (N_NODES * 64 + 255) / 256;   // 12500
    const int edgeBlocks = (E_EDGES + 255) / 256;

    // 1. LSTM -> A   (16 nodes per block, round-8 structure)
    lstm_mfma<<<N_NODES / 16, 256, 0, stream>>>(x, W_ih, W_hh, b_ih, b_hh, A);

    // 2. CSR build + normalization + combined weights
    hipMemsetAsync(cnt, 0, 50000 * sizeof(int), stream);
    hipMemsetAsync(gsum, 0, 1000 * sizeof(float), stream);
    count_deg<<<edgeBlocks, 256, 0, stream>>>(ei, cnt);
    make_dis<<<nodeBlocks, 256, 0, stream>>>(cnt, dis);
    scan_csr<<<1, 1024, 0, stream>>>(cnt, ptr, cursor);
    fill_csr<<<edgeBlocks, 256, 0, stream>>>(ei, cursor, csr);
    combine_w<<<(64 * 74 + 255) / 256, 256, 0, stream>>>(g1_W, l1_W, l1_b, Wc, bc);

    // 3. fused l1 + gcn1-transform: m -> C
    xform1<<<1024, 256, 0, stream>>>(A, sdi, Wc, bc, dis, C);

    // 4. fused gather + finalize + gcn2 transform: s2
    gatherfin1s2<<<featBlocks, 256, 0, stream>>>(ptr, csr, C, dis, g1_b, g2_W, s2);

    // 5. gather2 + pool
    gather2fin<<<nodeBlocks, 256, 0, stream>>>(ptr, csr, s2, dis, g2_b, batch, gsum, gcnt);
    pooldiv<<<2, 256, 0, stream>>>(gsum, gcnt, out);
}